// Round 11
// baseline (106.448 us; speedup 1.0000x reference)
//
#include <hip/hip_runtime.h>
#include <math.h>

#define INVT (1.0f / 0.07f)
#define CSHIFT (1.0f / 0.07f)

using bf16x8 = __attribute__((ext_vector_type(8))) short;
using f32x4  = __attribute__((ext_vector_type(4))) float;

__device__ __forceinline__ int lower_bound_i(const int* a, int n, int v) {
    int lo = 0, hi = n;
    while (lo < hi) { int mid = (lo + hi) >> 1; if (a[mid] < v) lo = mid + 1; else hi = mid; }
    return lo;
}

__device__ __forceinline__ unsigned short f2bf(float x) {
    unsigned int u = __float_as_uint(x);
    unsigned int r = (u + 0x7fffu + ((u >> 16) & 1u)) >> 16;   // RNE
    return (unsigned short)r;
}

__device__ __forceinline__ float agent_ld(const float* p) {
    return __hip_atomic_load(p, __ATOMIC_RELAXED, __HIP_MEMORY_SCOPE_AGENT);
}
__device__ __forceinline__ void agent_st(float* p, float v) {
    __hip_atomic_store(p, v, __ATOMIC_RELAXED, __HIP_MEMORY_SCOPE_AGENT);
}

// Load one 16-row fragment set directly from fp32, compute row norms in-wave,
// scale + convert to bf16 fragments held in registers. D must be 256 (8 k-tiles).
__device__ __forceinline__ void load_norm_set(const float* p, bf16x8* fr) {
    float4 v0[8], v1[8];
    float ss = 0.f;
    #pragma unroll
    for (int kt = 0; kt < 8; ++kt) {
        v0[kt] = *(const float4*)(p + kt * 32);
        v1[kt] = *(const float4*)(p + kt * 32 + 4);
        ss += v0[kt].x * v0[kt].x + v0[kt].y * v0[kt].y + v0[kt].z * v0[kt].z + v0[kt].w * v0[kt].w
            + v1[kt].x * v1[kt].x + v1[kt].y * v1[kt].y + v1[kt].z * v1[kt].z + v1[kt].w * v1[kt].w;
    }
    // lanes lhi=0..3 of same l15 cover the full row: reduce across lhi
    ss += __shfl_xor(ss, 16, 64);
    ss += __shfl_xor(ss, 32, 64);
    float inv = rsqrtf(ss);
    #pragma unroll
    for (int kt = 0; kt < 8; ++kt) {
        bf16x8 f;
        f[0] = (short)f2bf(v0[kt].x * inv);
        f[1] = (short)f2bf(v0[kt].y * inv);
        f[2] = (short)f2bf(v0[kt].z * inv);
        f[3] = (short)f2bf(v0[kt].w * inv);
        f[4] = (short)f2bf(v1[kt].x * inv);
        f[5] = (short)f2bf(v1[kt].y * inv);
        f[6] = (short)f2bf(v1[kt].z * inv);
        f[7] = (short)f2bf(v1[kt].w * inv);
        fr[kt] = f;
    }
}

// ---------------- single fused kernel ----------------
// grid (Nb/64, Nd/64), 256 threads. norm+cvt in registers -> 32 MFMAs ->
// epilogue -> slab agent-stores -> counter handoff -> parallel finishers -> loss.
__global__ __launch_bounds__(256, 2)
void k_all(const float* __restrict__ fb, const float* __restrict__ fd,
           const int* __restrict__ tb, const int* __restrict__ bb_arr,
           const int* __restrict__ td, const int* __restrict__ bd,
           const int* __restrict__ im, const int* __restrict__ ut,
           int Nb, int Nd, int D, int G,
           float* __restrict__ rowslab, float* __restrict__ colslab,
           float* __restrict__ mnum, float* __restrict__ m1, float* __restrict__ m3,
           float* __restrict__ t2g, float* __restrict__ bgs,
           unsigned int* __restrict__ rowcnt, unsigned int* __restrict__ colcnt,
           unsigned int* __restrict__ dcnt, float* __restrict__ out) {
    __shared__ float cnum[64], ct1[64], ct3[64], rsum[64];
    __shared__ int mwl[1024];
    __shared__ float red[256];
    __shared__ int rowflag, colflag, lastflag;

    int t = threadIdx.x, lane = t & 63, wid = t >> 6;
    int wr = wid >> 1, wc = wid & 1;
    int bm = blockIdx.x * 64, bn = blockIdx.y * 64;
    int l15 = lane & 15, lhi = lane >> 4;

    if (t < 64) { cnum[t] = 0.f; ct1[t] = 0.f; ct3[t] = 0.f; rsum[t] = 0.f; }
    // per-block mouth_word table
    for (int i = t; i < 1024; i += 256) mwl[i] = -1;
    __syncthreads();
    for (int j = t; j < Nd; j += 256) {
        if (im[j] == 1) atomicMax(&mwl[bd[j] & 1023], td[j]);
    }

    // ---- load + normalize + convert (register-resident fragments) ----
    const float* pa0 = fb + (size_t)(bm + wr * 32 + l15) * D + lhi * 8;
    const float* pa1 = pa0 + (size_t)16 * D;
    const float* pb0 = fd + (size_t)(bn + wc * 32 + l15) * D + lhi * 8;
    const float* pb1 = pb0 + (size_t)16 * D;

    bf16x8 fa0[8], fa1[8], fb0[8], fb1[8];
    load_norm_set(pa0, fa0);
    load_norm_set(pa1, fa1);
    load_norm_set(pb0, fb0);
    load_norm_set(pb1, fb1);

    // ---- 32 register-resident MFMAs ----
    f32x4 acc[2][2] = {};
    #pragma unroll
    for (int kt = 0; kt < 8; ++kt) {
        acc[0][0] = __builtin_amdgcn_mfma_f32_16x16x32_bf16(fa0[kt], fb0[kt], acc[0][0], 0, 0, 0);
        acc[0][1] = __builtin_amdgcn_mfma_f32_16x16x32_bf16(fa0[kt], fb1[kt], acc[0][1], 0, 0, 0);
        acc[1][0] = __builtin_amdgcn_mfma_f32_16x16x32_bf16(fa1[kt], fb0[kt], acc[1][0], 0, 0, 0);
        acc[1][1] = __builtin_amdgcn_mfma_f32_16x16x32_bf16(fa1[kt], fb1[kt], acc[1][1], 0, 0, 0);
    }

    // ---- epilogue ----
    int cgb[2], cgm[2], cgc[2];
    #pragma unroll
    for (int nj = 0; nj < 2; ++nj) {
        int col = bn + wc * 32 + nj * 16 + l15;
        cgb[nj] = bd[col]; cgm[nj] = im[col]; cgc[nj] = td[col];
    }

    float pnum[2] = {0.f, 0.f}, pt1[2] = {0.f, 0.f}, pt3[2] = {0.f, 0.f};
    float prow[2][4];

    #pragma unroll
    for (int mi = 0; mi < 2; ++mi) {
        #pragma unroll
        for (int r = 0; r < 4; ++r) {
            int i = bm + wr * 32 + mi * 16 + lhi * 4 + r;
            int tbi = tb[i], bbi = bb_arr[i];
            int mw = mwl[bbi & 1023];
            bool fg = (tbi != -1);
            float pr = 0.f;
            #pragma unroll
            for (int nj = 0; nj < 2; ++nj) {
                float e = __expf(acc[mi][nj][r] * INVT - CSHIFT);
                bool match = fg ? (cgc[nj] == mw) : ((cgb[nj] == bbi) && (cgm[nj] == 0));
                float a = (match && (bbi != cgb[nj])) ? 0.f : e;
                pnum[nj] += match ? e : 0.f;
                pt1[nj] += a;
                pt3[nj] += match ? a : 0.f;
                pr += a;
            }
            prow[mi][r] = pr;
        }
    }

    __syncthreads();

    #pragma unroll
    for (int nj = 0; nj < 2; ++nj) {
        float n = pnum[nj], x1 = pt1[nj], x3 = pt3[nj];
        n  += __shfl_xor(n, 16, 64);  n  += __shfl_xor(n, 32, 64);
        x1 += __shfl_xor(x1, 16, 64); x1 += __shfl_xor(x1, 32, 64);
        x3 += __shfl_xor(x3, 16, 64); x3 += __shfl_xor(x3, 32, 64);
        if (lhi == 0) {
            int c = wc * 32 + nj * 16 + l15;
            atomicAdd(&cnum[c], n); atomicAdd(&ct1[c], x1); atomicAdd(&ct3[c], x3);
        }
    }
    #pragma unroll
    for (int mi = 0; mi < 2; ++mi) {
        #pragma unroll
        for (int r = 0; r < 4; ++r) {
            float v = prow[mi][r];
            v += __shfl_xor(v, 1, 64); v += __shfl_xor(v, 2, 64);
            v += __shfl_xor(v, 4, 64); v += __shfl_xor(v, 8, 64);
            if (l15 == 0) atomicAdd(&rsum[wr * 32 + mi * 16 + lhi * 4 + r], v);
        }
    }
    __syncthreads();

    // ---- slab writes (agent-scope stores: visible cross-XCD at coherent point) ----
    if (t < 64) {
        agent_st(&rowslab[(size_t)blockIdx.y * Nb + bm + t], rsum[t]);
    } else {
        int c = (t - 64) & 63, arr = (t - 64) >> 6;
        float v = (arr == 0) ? cnum[c] : (arr == 1 ? ct1[c] : ct3[c]);
        agent_st(&colslab[((size_t)blockIdx.x * 3 + arr) * Nd + bn + c], v);
    }

    // ---- level-1 arrival ----
    asm volatile("s_waitcnt vmcnt(0)" ::: "memory");
    __syncthreads();
    if (t == 0) {
        rowflag = (atomicAdd(&rowcnt[blockIdx.x * 16], 1u) == gridDim.y - 1) ? 1 : 0;
        colflag = (atomicAdd(&colcnt[blockIdx.y * 16], 1u) == gridDim.x - 1) ? 1 : 0;
    }
    __syncthreads();
    int nfin = rowflag + colflag;
    if (nfin == 0) return;

    // ---- row finisher: merge gy slabs for rows bm..bm+63, scatter t2 pieces ----
    if (rowflag && t < 64) {
        int i = bm + t;
        float r = 0.f;
        for (int q = 0; q < (int)gridDim.y; ++q) r += agent_ld(&rowslab[(size_t)q * Nb + i]);
        int tbi = tb[i], bbi = bb_arr[i] & 1023;
        if (tbi != -1) {
            int g = lower_bound_i(ut, G, mwl[bbi]);
            atomicAdd(&t2g[g], r);
        } else {
            atomicAdd(&bgs[bbi], r);
        }
    }
    // ---- col finisher: merge gx slabs for cols bn..bn+63 ----
    if (colflag && t < 192) {
        int c = t / 3, arr = t - c * 3;
        int col = bn + c;
        float s0 = 0.f;
        for (int x = 0; x < (int)gridDim.x; ++x)
            s0 += agent_ld(&colslab[((size_t)x * 3 + arr) * Nd + col]);
        float* dst = (arr == 0 ? mnum : (arr == 1 ? m1 : m3)) + col;
        agent_st(dst, s0);
    }

    // ---- level-2 arrival ----
    asm volatile("s_waitcnt vmcnt(0)" ::: "memory");
    __syncthreads();
    if (t == 0) {
        unsigned int newv = atomicAdd(dcnt, (unsigned int)nfin) + (unsigned int)nfin;
        lastflag = (newv == gridDim.x + gridDim.y) ? 1 : 0;
    }
    __syncthreads();
    if (!lastflag) return;

    // ---- final block: group reduction + loss ----
    float acc2 = 0.f;
    for (int g = t; g < G; g += 256) {
        int s = lower_bound_i(td, Nd, ut[g]);
        int e = (g + 1 < G) ? lower_bound_i(td, Nd, ut[g + 1]) : Nd;
        float sn = 0.f, s1 = 0.f, s3 = 0.f;
        for (int c = s; c < e; ++c) {
            sn += agent_ld(&mnum[c]);
            s1 += agent_ld(&m1[c]);
            s3 += agent_ld(&m3[c]);
        }
        int gb = bd[s], gm = im[s];
        float t2 = agent_ld(&t2g[g]);
        if (gm == 0 && gb >= 0 && gb < 1024) t2 += agent_ld(&bgs[gb]);
        acc2 += logf(s1 + t2 - s3) - logf(sn);
    }
    red[t] = acc2;
    __syncthreads();
    for (int k = 128; k >= 1; k >>= 1) {
        if (t < k) red[t] += red[t + k];
        __syncthreads();
    }
    if (t == 0) out[0] = red[0] / (float)G;
}

extern "C" void kernel_launch(void* const* d_in, const int* in_sizes, int n_in,
                              void* d_out, int out_size, void* d_ws, size_t ws_size,
                              hipStream_t stream) {
    const float* fb = (const float*)d_in[0];
    const float* fd = (const float*)d_in[1];
    const int* tb = (const int*)d_in[2];
    const int* td = (const int*)d_in[3];
    const int* bb = (const int*)d_in[4];
    const int* bd = (const int*)d_in[5];
    const int* im = (const int*)d_in[6];
    const int* ut = (const int*)d_in[7];

    int Nb = in_sizes[2];
    int Nd = in_sizes[3];
    int G  = in_sizes[7];
    int D  = in_sizes[0] / Nb;
    float* out = (float*)d_out;

    int gx = Nb / 64, gy = Nd / 64;

    char* p = (char*)d_ws;
    float* rowslab = (float*)p; p += (size_t)gy * Nb * sizeof(float);
    float* colslab = (float*)p; p += (size_t)gx * 3 * Nd * sizeof(float);
    float* mnum = (float*)p; p += (size_t)Nd * sizeof(float);
    float* m1 = (float*)p;   p += (size_t)Nd * sizeof(float);
    float* m3 = (float*)p;   p += (size_t)Nd * sizeof(float);
    // ---- zeroed region (single small memset) ----
    char* zstart = p;
    float* t2g = (float*)p;  p += 1024 * sizeof(float);
    float* bgs = (float*)p;  p += 1024 * sizeof(float);
    unsigned int* rowcnt = (unsigned int*)p; p += (size_t)gx * 16 * sizeof(unsigned int);
    unsigned int* colcnt = (unsigned int*)p; p += (size_t)gy * 16 * sizeof(unsigned int);
    unsigned int* dcnt = (unsigned int*)p;   p += 16 * sizeof(unsigned int);
    size_t zbytes = (size_t)(p - zstart);

    hipMemsetAsync(zstart, 0, zbytes, stream);

    dim3 grid(gx, gy);
    k_all<<<grid, 256, 0, stream>>>(fb, fd, tb, bb, td, bd, im, ut,
                                    Nb, Nd, D, G,
                                    rowslab, colslab, mnum, m1, m3, t2g, bgs,
                                    rowcnt, colcnt, dcnt, out);
}

// Round 12
// 84.764 us; speedup vs baseline: 1.2558x; 1.2558x over previous
//
#include <hip/hip_runtime.h>
#include <math.h>

#define INVT (1.0f / 0.07f)
#define CSHIFT (1.0f / 0.07f)

using bf16x8 = __attribute__((ext_vector_type(8))) short;
using f32x4  = __attribute__((ext_vector_type(4))) float;

__device__ __forceinline__ int lower_bound_i(const int* a, int n, int v) {
    int lo = 0, hi = n;
    while (lo < hi) { int mid = (lo + hi) >> 1; if (a[mid] < v) lo = mid + 1; else hi = mid; }
    return lo;
}

__device__ __forceinline__ unsigned short f2bf(float x) {
    unsigned int u = __float_as_uint(x);
    unsigned int r = (u + 0x7fffu + ((u >> 16) & 1u)) >> 16;   // RNE
    return (unsigned short)r;
}

__device__ __forceinline__ float agent_ld(const float* p) {
    return __hip_atomic_load(p, __ATOMIC_RELAXED, __HIP_MEMORY_SCOPE_AGENT);
}
__device__ __forceinline__ void agent_st(float* p, float v) {
    __hip_atomic_store(p, v, __ATOMIC_RELAXED, __HIP_MEMORY_SCOPE_AGENT);
}

// Load one 16-row fragment set from fp32, norm in-wave, return bf16 fragments.
// Lane = lhi*16 + l15; reads row l15 (of the 16), k-chunk lhi*8 + kt*32. D==256.
__device__ __forceinline__ void load_norm_set(const float* p, bf16x8* fr) {
    float4 v0[8], v1[8];
    float ss = 0.f;
    #pragma unroll
    for (int kt = 0; kt < 8; ++kt) {
        v0[kt] = *(const float4*)(p + kt * 32);
        v1[kt] = *(const float4*)(p + kt * 32 + 4);
        ss += v0[kt].x * v0[kt].x + v0[kt].y * v0[kt].y + v0[kt].z * v0[kt].z + v0[kt].w * v0[kt].w
            + v1[kt].x * v1[kt].x + v1[kt].y * v1[kt].y + v1[kt].z * v1[kt].z + v1[kt].w * v1[kt].w;
    }
    ss += __shfl_xor(ss, 16, 64);
    ss += __shfl_xor(ss, 32, 64);
    float inv = rsqrtf(ss);
    #pragma unroll
    for (int kt = 0; kt < 8; ++kt) {
        bf16x8 f;
        f[0] = (short)f2bf(v0[kt].x * inv);
        f[1] = (short)f2bf(v0[kt].y * inv);
        f[2] = (short)f2bf(v0[kt].z * inv);
        f[3] = (short)f2bf(v0[kt].w * inv);
        f[4] = (short)f2bf(v1[kt].x * inv);
        f[5] = (short)f2bf(v1[kt].y * inv);
        f[6] = (short)f2bf(v1[kt].z * inv);
        f[7] = (short)f2bf(v1[kt].w * inv);
        fr[kt] = f;
    }
}

// ---------------- single fused kernel (B via LDS, A in regs — no spill) ----------------
__global__ __launch_bounds__(256, 2)
void k_all(const float* __restrict__ fb, const float* __restrict__ fd,
           const int* __restrict__ tb, const int* __restrict__ bb_arr,
           const int* __restrict__ td, const int* __restrict__ bd,
           const int* __restrict__ im, const int* __restrict__ ut,
           int Nb, int Nd, int D, int G,
           float* __restrict__ rowslab, float* __restrict__ colslab,
           float* __restrict__ mnum, float* __restrict__ m1, float* __restrict__ m3,
           float* __restrict__ t2g, float* __restrict__ bgs,
           unsigned int* __restrict__ rowcnt, unsigned int* __restrict__ colcnt,
           unsigned int* __restrict__ dcnt, float* __restrict__ out) {
    __shared__ __align__(16) short Bs[32 * 512];   // 32 tiles x 64 lanes x 8 bf16 = 32KB
    __shared__ float cnum[64], ct1[64], ct3[64], rsum[64];
    __shared__ int mwl[1024];
    __shared__ float red[256];
    __shared__ int rowflag, colflag, lastflag;

    int t = threadIdx.x, lane = t & 63, wid = t >> 6;
    int wr = wid >> 1, wc = wid & 1;
    int bm = blockIdx.x * 64, bn = blockIdx.y * 64;
    int l15 = lane & 15, lhi = lane >> 4;

    if (t < 64) { cnum[t] = 0.f; ct1[t] = 0.f; ct3[t] = 0.f; rsum[t] = 0.f; }
    for (int i = t; i < 1024; i += 256) mwl[i] = -1;
    __syncthreads();
    for (int j = t; j < Nd; j += 256) {
        if (im[j] == 1) atomicMax(&mwl[bd[j] & 1023], td[j]);
    }

    // ---- stage B tile (wave wid: rows bn + wid*16) -> LDS fragments ----
    {
        bf16x8 frB[8];
        load_norm_set(fd + (size_t)(bn + wid * 16 + l15) * D + lhi * 8, frB);
        #pragma unroll
        for (int kt = 0; kt < 8; ++kt)
            *(bf16x8*)&Bs[((wid * 8 + kt) * 64 + lane) * 8] = frB[kt];
    }
    // ---- A fragments in registers (rows bm + wr*32 .. +31) ----
    bf16x8 fa0[8], fa1[8];
    load_norm_set(fb + (size_t)(bm + wr * 32 + l15) * D + lhi * 8, fa0);
    load_norm_set(fb + (size_t)(bm + wr * 32 + 16 + l15) * D + lhi * 8, fa1);
    __syncthreads();   // covers mwl scan + Bs staging

    // ---- MFMA loop: 8 kt x {2 ds_read_b128, 4 MFMA} ----
    f32x4 acc[2][2] = {};
    #pragma unroll
    for (int kt = 0; kt < 8; ++kt) {
        bf16x8 b0 = *(const bf16x8*)&Bs[(((wc * 2 + 0) * 8 + kt) * 64 + lane) * 8];
        bf16x8 b1 = *(const bf16x8*)&Bs[(((wc * 2 + 1) * 8 + kt) * 64 + lane) * 8];
        acc[0][0] = __builtin_amdgcn_mfma_f32_16x16x32_bf16(fa0[kt], b0, acc[0][0], 0, 0, 0);
        acc[0][1] = __builtin_amdgcn_mfma_f32_16x16x32_bf16(fa0[kt], b1, acc[0][1], 0, 0, 0);
        acc[1][0] = __builtin_amdgcn_mfma_f32_16x16x32_bf16(fa1[kt], b0, acc[1][0], 0, 0, 0);
        acc[1][1] = __builtin_amdgcn_mfma_f32_16x16x32_bf16(fa1[kt], b1, acc[1][1], 0, 0, 0);
    }

    // ---- epilogue ----
    int cgb[2], cgm[2], cgc[2];
    #pragma unroll
    for (int nj = 0; nj < 2; ++nj) {
        int col = bn + wc * 32 + nj * 16 + l15;
        cgb[nj] = bd[col]; cgm[nj] = im[col]; cgc[nj] = td[col];
    }

    float pnum[2] = {0.f, 0.f}, pt1[2] = {0.f, 0.f}, pt3[2] = {0.f, 0.f};
    float prow[2][4];

    #pragma unroll
    for (int mi = 0; mi < 2; ++mi) {
        #pragma unroll
        for (int r = 0; r < 4; ++r) {
            int i = bm + wr * 32 + mi * 16 + lhi * 4 + r;
            int tbi = tb[i], bbi = bb_arr[i];
            int mw = mwl[bbi & 1023];
            bool fg = (tbi != -1);
            float pr = 0.f;
            #pragma unroll
            for (int nj = 0; nj < 2; ++nj) {
                float e = __expf(acc[mi][nj][r] * INVT - CSHIFT);
                bool match = fg ? (cgc[nj] == mw) : ((cgb[nj] == bbi) && (cgm[nj] == 0));
                float a = (match && (bbi != cgb[nj])) ? 0.f : e;
                pnum[nj] += match ? e : 0.f;
                pt1[nj] += a;
                pt3[nj] += match ? a : 0.f;
                pr += a;
            }
            prow[mi][r] = pr;
        }
    }

    __syncthreads();

    #pragma unroll
    for (int nj = 0; nj < 2; ++nj) {
        float n = pnum[nj], x1 = pt1[nj], x3 = pt3[nj];
        n  += __shfl_xor(n, 16, 64);  n  += __shfl_xor(n, 32, 64);
        x1 += __shfl_xor(x1, 16, 64); x1 += __shfl_xor(x1, 32, 64);
        x3 += __shfl_xor(x3, 16, 64); x3 += __shfl_xor(x3, 32, 64);
        if (lhi == 0) {
            int c = wc * 32 + nj * 16 + l15;
            atomicAdd(&cnum[c], n); atomicAdd(&ct1[c], x1); atomicAdd(&ct3[c], x3);
        }
    }
    #pragma unroll
    for (int mi = 0; mi < 2; ++mi) {
        #pragma unroll
        for (int r = 0; r < 4; ++r) {
            float v = prow[mi][r];
            v += __shfl_xor(v, 1, 64); v += __shfl_xor(v, 2, 64);
            v += __shfl_xor(v, 4, 64); v += __shfl_xor(v, 8, 64);
            if (l15 == 0) atomicAdd(&rsum[wr * 32 + mi * 16 + lhi * 4 + r], v);
        }
    }
    __syncthreads();

    // ---- slab writes ----
    if (t < 64) {
        agent_st(&rowslab[(size_t)blockIdx.y * Nb + bm + t], rsum[t]);
    } else {
        int c = (t - 64) & 63, arr = (t - 64) >> 6;
        float v = (arr == 0) ? cnum[c] : (arr == 1 ? ct1[c] : ct3[c]);
        agent_st(&colslab[((size_t)blockIdx.x * 3 + arr) * Nd + bn + c], v);
    }

    // ---- level-1 arrival ----
    asm volatile("s_waitcnt vmcnt(0)" ::: "memory");
    __syncthreads();
    if (t == 0) {
        rowflag = (atomicAdd(&rowcnt[blockIdx.x * 16], 1u) == gridDim.y - 1) ? 1 : 0;
        colflag = (atomicAdd(&colcnt[blockIdx.y * 16], 1u) == gridDim.x - 1) ? 1 : 0;
    }
    __syncthreads();
    int nfin = rowflag + colflag;
    if (nfin == 0) return;

    // ---- row finisher ----
    if (rowflag && t < 64) {
        int i = bm + t;
        float r = 0.f;
        for (int q = 0; q < (int)gridDim.y; ++q) r += agent_ld(&rowslab[(size_t)q * Nb + i]);
        int tbi = tb[i], bbi = bb_arr[i] & 1023;
        if (tbi != -1) {
            int g = lower_bound_i(ut, G, mwl[bbi]);
            atomicAdd(&t2g[g], r);
        } else {
            atomicAdd(&bgs[bbi], r);
        }
    }
    // ---- col finisher ----
    if (colflag && t < 192) {
        int c = t / 3, arr = t - c * 3;
        int col = bn + c;
        float s0 = 0.f;
        for (int x = 0; x < (int)gridDim.x; ++x)
            s0 += agent_ld(&colslab[((size_t)x * 3 + arr) * Nd + col]);
        float* dst = (arr == 0 ? mnum : (arr == 1 ? m1 : m3)) + col;
        agent_st(dst, s0);
    }

    // ---- level-2 arrival ----
    asm volatile("s_waitcnt vmcnt(0)" ::: "memory");
    __syncthreads();
    if (t == 0) {
        unsigned int newv = atomicAdd(dcnt, (unsigned int)nfin) + (unsigned int)nfin;
        lastflag = (newv == gridDim.x + gridDim.y) ? 1 : 0;
    }
    __syncthreads();
    if (!lastflag) return;

    // ---- final block: group reduction + loss ----
    float acc2 = 0.f;
    for (int g = t; g < G; g += 256) {
        int s = lower_bound_i(td, Nd, ut[g]);
        int e = (g + 1 < G) ? lower_bound_i(td, Nd, ut[g + 1]) : Nd;
        float sn = 0.f, s1 = 0.f, s3 = 0.f;
        for (int c = s; c < e; ++c) {
            sn += agent_ld(&mnum[c]);
            s1 += agent_ld(&m1[c]);
            s3 += agent_ld(&m3[c]);
        }
        int gb = bd[s], gm = im[s];
        float t2 = agent_ld(&t2g[g]);
        if (gm == 0 && gb >= 0 && gb < 1024) t2 += agent_ld(&bgs[gb]);
        acc2 += logf(s1 + t2 - s3) - logf(sn);
    }
    red[t] = acc2;
    __syncthreads();
    for (int k = 128; k >= 1; k >>= 1) {
        if (t < k) red[t] += red[t + k];
        __syncthreads();
    }
    if (t == 0) out[0] = red[0] / (float)G;
}

extern "C" void kernel_launch(void* const* d_in, const int* in_sizes, int n_in,
                              void* d_out, int out_size, void* d_ws, size_t ws_size,
                              hipStream_t stream) {
    const float* fb = (const float*)d_in[0];
    const float* fd = (const float*)d_in[1];
    const int* tb = (const int*)d_in[2];
    const int* td = (const int*)d_in[3];
    const int* bb = (const int*)d_in[4];
    const int* bd = (const int*)d_in[5];
    const int* im = (const int*)d_in[6];
    const int* ut = (const int*)d_in[7];

    int Nb = in_sizes[2];
    int Nd = in_sizes[3];
    int G  = in_sizes[7];
    int D  = in_sizes[0] / Nb;
    float* out = (float*)d_out;

    int gx = Nb / 64, gy = Nd / 64;

    char* p = (char*)d_ws;
    float* rowslab = (float*)p; p += (size_t)gy * Nb * sizeof(float);
    float* colslab = (float*)p; p += (size_t)gx * 3 * Nd * sizeof(float);
    float* mnum = (float*)p; p += (size_t)Nd * sizeof(float);
    float* m1 = (float*)p;   p += (size_t)Nd * sizeof(float);
    float* m3 = (float*)p;   p += (size_t)Nd * sizeof(float);
    // ---- zeroed region (single small memset) ----
    char* zstart = p;
    float* t2g = (float*)p;  p += 1024 * sizeof(float);
    float* bgs = (float*)p;  p += 1024 * sizeof(float);
    unsigned int* rowcnt = (unsigned int*)p; p += (size_t)gx * 16 * sizeof(unsigned int);
    unsigned int* colcnt = (unsigned int*)p; p += (size_t)gy * 16 * sizeof(unsigned int);
    unsigned int* dcnt = (unsigned int*)p;   p += 16 * sizeof(unsigned int);
    size_t zbytes = (size_t)(p - zstart);

    hipMemsetAsync(zstart, 0, zbytes, stream);

    dim3 grid(gx, gy);
    k_all<<<grid, 256, 0, stream>>>(fb, fd, tb, bb, td, bd, im, ut,
                                    Nb, Nd, D, G,
                                    rowslab, colslab, mnum, m1, m3, t2g, bgs,
                                    rowcnt, colcnt, dcnt, out);
}

// Round 13
// 56.898 us; speedup vs baseline: 1.8709x; 1.4898x over previous
//
#include <hip/hip_runtime.h>
#include <math.h>

#define INVT (1.0f / 0.07f)
#define CSHIFT (1.0f / 0.07f)

using bf16x8 = __attribute__((ext_vector_type(8))) short;
using f32x4  = __attribute__((ext_vector_type(4))) float;

__device__ __forceinline__ int lower_bound_i(const int* a, int n, int v) {
    int lo = 0, hi = n;
    while (lo < hi) { int mid = (lo + hi) >> 1; if (a[mid] < v) lo = mid + 1; else hi = mid; }
    return lo;
}

__device__ __forceinline__ unsigned short f2bf(float x) {
    unsigned int u = __float_as_uint(x);
    unsigned int r = (u + 0x7fffu + ((u >> 16) & 1u)) >> 16;   // RNE
    return (unsigned short)r;
}

__device__ __forceinline__ float agent_ld(const float* p) {
    return __hip_atomic_load(p, __ATOMIC_RELAXED, __HIP_MEMORY_SCOPE_AGENT);
}
__device__ __forceinline__ void agent_st(float* p, float v) {
    __hip_atomic_store(p, v, __ATOMIC_RELAXED, __HIP_MEMORY_SCOPE_AGENT);
}

// ---------------- kernel 1: LDS-transposed prep (R9 version, proven) ----------------
__global__ __launch_bounds__(256)
void k_prep(const float* __restrict__ fb, const float* __restrict__ fd,
            int Nb, int Nd, int D,
            unsigned short* __restrict__ fbt, unsigned short* __restrict__ fdt,
            unsigned int* __restrict__ zbase, int zcount,
            const int* __restrict__ td, const int* __restrict__ bd,
            const int* __restrict__ im,
            int* __restrict__ mouth_word) {
    __shared__ __align__(16) unsigned short lbuf[32 * 256];
    int t = threadIdx.x;

    int nthreads = gridDim.x * blockDim.x;
    for (int zi = blockIdx.x * blockDim.x + t; zi < zcount; zi += nthreads) zbase[zi] = 0u;

    if (blockIdx.x == 0) {
        for (int i = t; i < Nb; i += blockDim.x) mouth_word[i] = -1;
        __syncthreads();
        for (int j = t; j < Nd; j += blockDim.x) {
            if (im[j] == 1) atomicMax(&mouth_word[bd[j]], td[j]);
        }
    }

    int R0 = blockIdx.x * 32;
    if (R0 >= Nb + Nd) return;
    const float* src; unsigned short* dst; int rt0;
    if (R0 < Nb) { src = fb + (size_t)R0 * D; dst = fbt; rt0 = R0 >> 4; }
    else         { src = fd + (size_t)(R0 - Nb) * D; dst = fdt; rt0 = (R0 - Nb) >> 4; }

    int row = t >> 3, kp = t & 7;
    const float* rp = src + (size_t)row * D;
    float4 v[8];
    float ss = 0.f;
    #pragma unroll
    for (int i = 0; i < 8; ++i) {
        v[i] = *(const float4*)(rp + 4 * (kp + 8 * i));
        ss += v[i].x * v[i].x + v[i].y * v[i].y + v[i].z * v[i].z + v[i].w * v[i].w;
    }
    ss += __shfl_xor(ss, 1, 64);
    ss += __shfl_xor(ss, 2, 64);
    ss += __shfl_xor(ss, 4, 64);
    float inv = rsqrtf(ss);
    #pragma unroll
    for (int i = 0; i < 8; ++i) {
        ushort4 o;
        o.x = f2bf(v[i].x * inv); o.y = f2bf(v[i].y * inv);
        o.z = f2bf(v[i].z * inv); o.w = f2bf(v[i].w * inv);
        *(ushort4*)&lbuf[row * 256 + 4 * (kp + 8 * i)] = o;
    }
    __syncthreads();

    int ktiles = D >> 5;
    #pragma unroll
    for (int j = 0; j < 4; ++j) {
        int c = t + 256 * j;
        int tile = c >> 6, l = c & 63;
        int rtl = tile >> 3, kt = tile & 7;
        int srow = rtl * 16 + (l & 15), sk = kt * 32 + (l >> 4) * 8;
        ulonglong2 d = *(const ulonglong2*)&lbuf[srow * 256 + sk];
        *(ulonglong2*)(dst + (((size_t)((rt0 + rtl) * ktiles + kt)) << 9) + l * 8) = d;
    }
}

// ---------------- kernel 2: pure MFMA GEMM + epilogue, plain slab stores ----------------
// NO atomics, NO waitcnt drain, NO counters — kernel boundary provides visibility.
__global__ __launch_bounds__(256, 4)
void k_main(const unsigned short* __restrict__ fbt, const unsigned short* __restrict__ fdt,
            const int* __restrict__ tb, const int* __restrict__ bb_arr,
            const int* __restrict__ td, const int* __restrict__ bd,
            const int* __restrict__ im, const int* __restrict__ mouth_word,
            int Nb, int Nd, int D,
            float* __restrict__ rowslab, float* __restrict__ colslab) {
    __shared__ float cnum[64], ct1[64], ct3[64], rsum[64];

    int t = threadIdx.x, lane = t & 63, wid = t >> 6;
    int wr = wid >> 1, wc = wid & 1;
    int bm = blockIdx.x * 64, bn = blockIdx.y * 64;
    int l15 = lane & 15, lhi = lane >> 4;

    if (t < 64) { cnum[t] = 0.f; ct1[t] = 0.f; ct3[t] = 0.f; rsum[t] = 0.f; }

    int ktiles = D >> 5;
    const unsigned short* a0p = fbt + (((size_t)(((bm >> 4) + wr * 2) * ktiles)) << 9) + lane * 8;
    const unsigned short* a1p = a0p + ((size_t)ktiles << 9);
    const unsigned short* b0p = fdt + (((size_t)(((bn >> 4) + wc * 2) * ktiles)) << 9) + lane * 8;
    const unsigned short* b1p = b0p + ((size_t)ktiles << 9);

    f32x4 acc[2][2] = {};
    bf16x8 ca0 = *(const bf16x8*)a0p;
    bf16x8 ca1 = *(const bf16x8*)a1p;
    bf16x8 cb0 = *(const bf16x8*)b0p;
    bf16x8 cb1 = *(const bf16x8*)b1p;
    size_t o = 0;
    #pragma unroll 7
    for (int kt = 0; kt + 1 < ktiles; ++kt) {
        o += 512;
        bf16x8 na0 = *(const bf16x8*)(a0p + o);
        bf16x8 na1 = *(const bf16x8*)(a1p + o);
        bf16x8 nb0 = *(const bf16x8*)(b0p + o);
        bf16x8 nb1 = *(const bf16x8*)(b1p + o);
        acc[0][0] = __builtin_amdgcn_mfma_f32_16x16x32_bf16(ca0, cb0, acc[0][0], 0, 0, 0);
        acc[0][1] = __builtin_amdgcn_mfma_f32_16x16x32_bf16(ca0, cb1, acc[0][1], 0, 0, 0);
        acc[1][0] = __builtin_amdgcn_mfma_f32_16x16x32_bf16(ca1, cb0, acc[1][0], 0, 0, 0);
        acc[1][1] = __builtin_amdgcn_mfma_f32_16x16x32_bf16(ca1, cb1, acc[1][1], 0, 0, 0);
        ca0 = na0; ca1 = na1; cb0 = nb0; cb1 = nb1;
    }
    acc[0][0] = __builtin_amdgcn_mfma_f32_16x16x32_bf16(ca0, cb0, acc[0][0], 0, 0, 0);
    acc[0][1] = __builtin_amdgcn_mfma_f32_16x16x32_bf16(ca0, cb1, acc[0][1], 0, 0, 0);
    acc[1][0] = __builtin_amdgcn_mfma_f32_16x16x32_bf16(ca1, cb0, acc[1][0], 0, 0, 0);
    acc[1][1] = __builtin_amdgcn_mfma_f32_16x16x32_bf16(ca1, cb1, acc[1][1], 0, 0, 0);

    // ---- epilogue ----
    int cgb[2], cgm[2], cgc[2];
    #pragma unroll
    for (int nj = 0; nj < 2; ++nj) {
        int col = bn + wc * 32 + nj * 16 + l15;
        cgb[nj] = bd[col]; cgm[nj] = im[col]; cgc[nj] = td[col];
    }

    float pnum[2] = {0.f, 0.f}, pt1[2] = {0.f, 0.f}, pt3[2] = {0.f, 0.f};
    float prow[2][4];

    #pragma unroll
    for (int mi = 0; mi < 2; ++mi) {
        #pragma unroll
        for (int r = 0; r < 4; ++r) {
            int i = bm + wr * 32 + mi * 16 + lhi * 4 + r;
            int tbi = tb[i], bbi = bb_arr[i];
            int mw = mouth_word[bbi];
            bool fg = (tbi != -1);
            float pr = 0.f;
            #pragma unroll
            for (int nj = 0; nj < 2; ++nj) {
                float e = __expf(acc[mi][nj][r] * INVT - CSHIFT);
                bool match = fg ? (cgc[nj] == mw) : ((cgb[nj] == bbi) && (cgm[nj] == 0));
                float a = (match && (bbi != cgb[nj])) ? 0.f : e;
                pnum[nj] += match ? e : 0.f;
                pt1[nj] += a;
                pt3[nj] += match ? a : 0.f;
                pr += a;
            }
            prow[mi][r] = pr;
        }
    }

    __syncthreads();

    #pragma unroll
    for (int nj = 0; nj < 2; ++nj) {
        float n = pnum[nj], x1 = pt1[nj], x3 = pt3[nj];
        n  += __shfl_xor(n, 16, 64);  n  += __shfl_xor(n, 32, 64);
        x1 += __shfl_xor(x1, 16, 64); x1 += __shfl_xor(x1, 32, 64);
        x3 += __shfl_xor(x3, 16, 64); x3 += __shfl_xor(x3, 32, 64);
        if (lhi == 0) {
            int c = wc * 32 + nj * 16 + l15;
            atomicAdd(&cnum[c], n); atomicAdd(&ct1[c], x1); atomicAdd(&ct3[c], x3);
        }
    }
    #pragma unroll
    for (int mi = 0; mi < 2; ++mi) {
        #pragma unroll
        for (int r = 0; r < 4; ++r) {
            float v = prow[mi][r];
            v += __shfl_xor(v, 1, 64); v += __shfl_xor(v, 2, 64);
            v += __shfl_xor(v, 4, 64); v += __shfl_xor(v, 8, 64);
            if (l15 == 0) atomicAdd(&rsum[wr * 32 + mi * 16 + lhi * 4 + r], v);
        }
    }
    __syncthreads();

    // ---- plain coalesced slab stores (unique writer per slot) ----
    if (t < 64) {
        rowslab[(size_t)blockIdx.y * Nb + bm + t] = rsum[t];
    } else {
        int c = (t - 64) & 63, arr = (t - 64) >> 6;
        float v = (arr == 0) ? cnum[c] : (arr == 1 ? ct1[c] : ct3[c]);
        colslab[((size_t)blockIdx.x * 3 + arr) * Nd + bn + c] = v;
    }
}

// ---------------- kernel 3: parallel finish (80 blocks) ----------------
// blocks 0..gx-1: row merge + t2 scatter. blocks gx..gx+gy-1: col merge.
// last arrival computes the loss.
__global__ __launch_bounds__(256)
void k_fin(const int* __restrict__ tb, const int* __restrict__ bb_arr,
           const int* __restrict__ td, const int* __restrict__ bd,
           const int* __restrict__ im, const int* __restrict__ ut,
           const int* __restrict__ mouth_word,
           int Nb, int Nd, int G, int gx, int gy,
           const float* __restrict__ rowslab, const float* __restrict__ colslab,
           float* __restrict__ mnum, float* __restrict__ m1, float* __restrict__ m3,
           float* __restrict__ t2g, float* __restrict__ bgs,
           unsigned int* __restrict__ dcnt, float* __restrict__ out) {
    __shared__ float red[256];
    __shared__ int lastflag;
    int t = threadIdx.x;
    int b = blockIdx.x;

    if (b < gx) {
        // row finisher: rows b*64 .. +63 (plain loads — kernel boundary visibility)
        if (t < 64) {
            int i = b * 64 + t;
            float r = 0.f;
            for (int q = 0; q < gy; ++q) r += rowslab[(size_t)q * Nb + i];
            int tbi = tb[i], bbi = bb_arr[i] & 1023;
            if (tbi != -1) {
                int g = lower_bound_i(ut, G, mouth_word[bbi]);
                atomicAdd(&t2g[g], r);
            } else {
                atomicAdd(&bgs[bbi], r);
            }
        }
    } else {
        // col finisher: cols (b-gx)*64 .. +63, 3 arrays -> 192 tasks
        int by = b - gx;
        if (t < 192) {
            int c = t / 3, arr = t - c * 3;
            int col = by * 64 + c;
            float s0 = 0.f;
            for (int x = 0; x < gx; ++x)
                s0 += colslab[((size_t)x * 3 + arr) * Nd + col];
            float* dst = (arr == 0 ? mnum : (arr == 1 ? m1 : m3)) + col;
            agent_st(dst, s0);
        }
    }

    // arrival
    asm volatile("s_waitcnt vmcnt(0)" ::: "memory");
    __syncthreads();
    if (t == 0) {
        unsigned int old = atomicAdd(dcnt, 1u);
        lastflag = (old == (unsigned int)(gx + gy - 1)) ? 1 : 0;
    }
    __syncthreads();
    if (!lastflag) return;

    // final: group reduction + loss
    float acc2 = 0.f;
    for (int g = t; g < G; g += 256) {
        int s = lower_bound_i(td, Nd, ut[g]);
        int e = (g + 1 < G) ? lower_bound_i(td, Nd, ut[g + 1]) : Nd;
        float sn = 0.f, s1 = 0.f, s3 = 0.f;
        for (int c = s; c < e; ++c) {
            sn += agent_ld(&mnum[c]);
            s1 += agent_ld(&m1[c]);
            s3 += agent_ld(&m3[c]);
        }
        int gb = bd[s], gm = im[s];
        float t2 = agent_ld(&t2g[g]);
        if (gm == 0 && gb >= 0 && gb < 1024) t2 += agent_ld(&bgs[gb]);
        acc2 += logf(s1 + t2 - s3) - logf(sn);
    }
    red[t] = acc2;
    __syncthreads();
    for (int k = 128; k >= 1; k >>= 1) {
        if (t < k) red[t] += red[t + k];
        __syncthreads();
    }
    if (t == 0) out[0] = red[0] / (float)G;
}

extern "C" void kernel_launch(void* const* d_in, const int* in_sizes, int n_in,
                              void* d_out, int out_size, void* d_ws, size_t ws_size,
                              hipStream_t stream) {
    const float* fb = (const float*)d_in[0];
    const float* fd = (const float*)d_in[1];
    const int* tb = (const int*)d_in[2];
    const int* td = (const int*)d_in[3];
    const int* bb = (const int*)d_in[4];
    const int* bd = (const int*)d_in[5];
    const int* im = (const int*)d_in[6];
    const int* ut = (const int*)d_in[7];

    int Nb = in_sizes[2];
    int Nd = in_sizes[3];
    int G  = in_sizes[7];
    int D  = in_sizes[0] / Nb;
    float* out = (float*)d_out;

    int gx = Nb / 64, gy = Nd / 64;

    char* p = (char*)d_ws;
    unsigned short* fbt = (unsigned short*)p; p += (size_t)Nb * D * sizeof(unsigned short);
    unsigned short* fdt = (unsigned short*)p; p += (size_t)Nd * D * sizeof(unsigned short);
    float* rowslab = (float*)p; p += (size_t)gy * Nb * sizeof(float);
    float* colslab = (float*)p; p += (size_t)gx * 3 * Nd * sizeof(float);
    float* mnum = (float*)p; p += (size_t)Nd * sizeof(float);
    float* m1 = (float*)p;   p += (size_t)Nd * sizeof(float);
    float* m3 = (float*)p;   p += (size_t)Nd * sizeof(float);
    int* mouth_word = (int*)p; p += (size_t)Nb * sizeof(int);
    // ---- zeroed region (done inside k_prep) ----
    char* zstart = p;
    float* t2g = (float*)p;  p += 1024 * sizeof(float);
    float* bgs = (float*)p;  p += 1024 * sizeof(float);
    unsigned int* dcnt = (unsigned int*)p; p += 16 * sizeof(unsigned int);
    int zcount = (int)((p - zstart) / 4);

    {
        int blocks = (Nb + Nd) / 32;
        k_prep<<<blocks, 256, 0, stream>>>(fb, fd, Nb, Nd, D, fbt, fdt,
                                           (unsigned int*)zstart, zcount,
                                           td, bd, im, mouth_word);
    }

    dim3 grid(gx, gy);
    k_main<<<grid, 256, 0, stream>>>(fbt, fdt, tb, bb, td, bd, im, mouth_word,
                                     Nb, Nd, D, rowslab, colslab);

    k_fin<<<gx + gy, 256, 0, stream>>>(tb, bb, td, bd, im, ut, mouth_word,
                                       Nb, Nd, G, gx, gy,
                                       rowslab, colslab, mnum, m1, m3, t2g, bgs,
                                       dcnt, out);
}